// Round 1
// baseline (1768.019 us; speedup 1.0000x reference)
//
#include <hip/hip_runtime.h>
#include <math.h>

#define N_TOK 8192
#define DIM   1024
#define HID   2048
#define NE    8
#define NPAIR (N_TOK * 2)          // 16384 (token, expert) pairs exactly
#define CAP   (NPAIR + 128)        // pad so last row-tile reads stay in bounds
#define TAIL  (N_TOK * DIM)        // 8388608: offset of scalar outputs in d_out

typedef __bf16 bf16x8_t __attribute__((ext_vector_type(8)));
typedef float  f32x4_t  __attribute__((ext_vector_type(4)));

__device__ __forceinline__ unsigned short f2bf(float f) {
  union { float f; unsigned u; } v; v.f = f;
  unsigned r = v.u + 0x7fffu + ((v.u >> 16) & 1u);   // RNE
  return (unsigned short)(r >> 16);
}

__device__ __forceinline__ float gelu_exact(float v) {
  return 0.5f * v * (1.f + erff(v * 0.70710678118654752440f));
}

// ---------------- x -> bf16 ----------------
__global__ __launch_bounds__(256) void cvt_x_kernel(const float* __restrict__ x,
                                                    unsigned short* __restrict__ xbf) {
  size_t base = (size_t)(blockIdx.x * 256 + threadIdx.x) * 4;
  float4 v = *(const float4*)(x + base);
  ushort4 o;
  o.x = f2bf(v.x); o.y = f2bf(v.y); o.z = f2bf(v.z); o.w = f2bf(v.w);
  *(ushort4*)(xbf + base) = o;
}

// ---------------- fp32 [z][R][C] -> bf16 [z][C][R] (LDS-tiled) ----------------
__global__ __launch_bounds__(256) void transpose_kernel(const float* __restrict__ src,
                                                        unsigned short* __restrict__ dst,
                                                        int R, int C) {
  __shared__ float tile[32][33];
  int z = blockIdx.z;
  const float* s = src + (size_t)z * R * C;
  unsigned short* d = dst + (size_t)z * R * C;
  int c0 = blockIdx.x * 32, r0 = blockIdx.y * 32;
  int tx = threadIdx.x & 31, ty = threadIdx.x >> 5;   // 32 x 8
  #pragma unroll
  for (int i = 0; i < 32; i += 8)
    tile[ty + i][tx] = s[(size_t)(r0 + ty + i) * C + c0 + tx];
  __syncthreads();
  #pragma unroll
  for (int i = 0; i < 32; i += 8)
    d[(size_t)(c0 + ty + i) * R + r0 + tx] = f2bf(tile[tx][ty + i]);
}

// ---------------- router: logits (fp32), top-2, softmax, aux stats ----------------
__global__ __launch_bounds__(256) void router_kernel(
    const float* __restrict__ x, const float* __restrict__ gW, const float* __restrict__ gb,
    int* __restrict__ tok_e, float* __restrict__ tok_g,
    int* __restrict__ cnt, float* __restrict__ imp, float* __restrict__ ent_sum) {
  int wid = threadIdx.x >> 6, lane = threadIdx.x & 63;
  int n = blockIdx.x * 4 + wid;                 // one wave per token
  const float* xr = x + (size_t)n * DIM;
  float p[8] = {0.f, 0.f, 0.f, 0.f, 0.f, 0.f, 0.f, 0.f};
  #pragma unroll
  for (int it = 0; it < DIM / 64; ++it) {
    int d = lane + (it << 6);
    float xv = xr[d];
    const float4* g4 = (const float4*)(gW + (size_t)d * NE);
    float4 a = g4[0], b = g4[1];
    p[0] += xv * a.x; p[1] += xv * a.y; p[2] += xv * a.z; p[3] += xv * a.w;
    p[4] += xv * b.x; p[5] += xv * b.y; p[6] += xv * b.z; p[7] += xv * b.w;
  }
  #pragma unroll
  for (int e = 0; e < 8; ++e)
    for (int o = 32; o > 0; o >>= 1) p[e] += __shfl_down(p[e], o, 64);
  if (lane == 0) {
    float lg[8];
    #pragma unroll
    for (int e = 0; e < 8; ++e) lg[e] = p[e] + gb[e];
    int i0 = 0;
    #pragma unroll
    for (int e = 1; e < 8; ++e) if (lg[e] > lg[i0]) i0 = e;     // ties -> lowest idx
    int i1 = (i0 == 0) ? 1 : 0;
    #pragma unroll
    for (int e = 0; e < 8; ++e) if (e != i0 && lg[e] > lg[i1]) i1 = e;
    float d1 = expf(lg[i1] - lg[i0]);
    float g0 = 1.f / (1.f + d1);
    float g1 = d1 * g0;
    tok_e[2 * n] = i0; tok_e[2 * n + 1] = i1;
    tok_g[2 * n] = g0; tok_g[2 * n + 1] = g1;
    atomicAdd(&cnt[i0], 1);
    atomicAdd(&cnt[i1], 1);
    float mx = lg[i0], s = 0.f, pe[8];
    #pragma unroll
    for (int e = 0; e < 8; ++e) { pe[e] = expf(lg[e] - mx); s += pe[e]; }
    float inv = 1.f / s, ent = 0.f;
    const float invN = 1.f / (float)N_TOK;
    #pragma unroll
    for (int e = 0; e < 8; ++e) {
      float pr = pe[e] * inv;
      atomicAdd(&imp[e], pr * invN);
      ent -= pr * logf(pr + 1e-8f);
    }
    atomicAdd(ent_sum, ent * invN);
  }
}

// ---------------- finalize: offsets/cursors + scalar outputs ----------------
__global__ void finalize_kernel(const int* __restrict__ cnt, int* __restrict__ offs,
                                int* __restrict__ cursor, const float* __restrict__ imp,
                                const float* __restrict__ ent_sum, float* __restrict__ out_tail) {
  if (threadIdx.x == 0) {
    int off = 0; float bal = 0.f, util = 0.f;
    for (int e = 0; e < NE; ++e) {
      offs[e] = off; cursor[e] = off; off += cnt[e];
      float ld = (float)cnt[e] * (1.f / (float)N_TOK);
      float im = imp[e];
      out_tail[3 + e] = ld;        // load
      out_tail[11 + e] = im;       // importance
      bal += im * ld;
      util -= ld * logf(ld + 1e-8f);
    }
    out_tail[0] = (float)NE * bal; // balance_loss
    out_tail[1] = *ent_sum;        // entropy
    out_tail[2] = util;            // utilization_entropy
  }
}

// ---------------- scatter pairs into expert buckets ----------------
__global__ __launch_bounds__(256) void scatter_kernel(
    const int* __restrict__ tok_e, const float* __restrict__ tok_g,
    int* __restrict__ cursor, int* __restrict__ row_token, float* __restrict__ row_gate) {
  int n = blockIdx.x * 256 + threadIdx.x;
  if (n >= N_TOK) return;
  #pragma unroll
  for (int k = 0; k < 2; ++k) {
    int e = tok_e[2 * n + k];
    int s = atomicAdd(&cursor[e], 1);
    row_token[s] = n;
    row_gate[s] = tok_g[2 * n + k];
  }
}

// ---------------- GEMM1: He = gelu(X_gather @ W1[e] + b1[e]), bf16 out ----------------
__global__ __launch_bounds__(256, 2) void expert_gemm1(
    const unsigned short* __restrict__ xbf,   // [N][D] bf16
    const unsigned short* __restrict__ W1T,   // [E][H][D] bf16
    const float* __restrict__ b1,             // [E][H]
    const int* __restrict__ cnt, const int* __restrict__ offs,
    const int* __restrict__ row_token,
    unsigned short* __restrict__ He) {        // [CAP][H] bf16
  __shared__ unsigned short As[128 * 72];
  __shared__ unsigned short Bs[128 * 72];
  __shared__ int toks[128];
  int e = blockIdx.z;
  int c_e = cnt[e];
  int row0 = blockIdx.x * 128;
  if (row0 >= c_e) return;
  int col0 = blockIdx.y * 128;
  int off = offs[e];
  int tid = threadIdx.x;
  if (tid < 128) {
    int r = row0 + tid;
    toks[tid] = (r < c_e) ? row_token[off + r] : 0;
  }
  __syncthreads();
  f32x4_t zero4 = {0.f, 0.f, 0.f, 0.f};
  f32x4_t acc[4][4];
  #pragma unroll
  for (int i = 0; i < 4; ++i)
    #pragma unroll
    for (int j = 0; j < 4; ++j) acc[i][j] = zero4;
  const unsigned short* Bg = W1T + (size_t)e * HID * DIM;
  int wid = tid >> 6, lane = tid & 63;
  int wr = (wid & 1) << 6, wc = (wid >> 1) << 6;
  int m16 = lane & 15, q = lane >> 4;
  for (int k0 = 0; k0 < DIM; k0 += 64) {
    #pragma unroll
    for (int i = 0; i < 4; ++i) {
      int c = tid + (i << 8);
      int r = c >> 3, kc = c & 7;
      *(uint4*)&As[r * 72 + kc * 8] = *(const uint4*)&xbf[(size_t)toks[r] * DIM + k0 + kc * 8];
      *(uint4*)&Bs[r * 72 + kc * 8] = *(const uint4*)&Bg[(size_t)(col0 + r) * DIM + k0 + kc * 8];
    }
    __syncthreads();
    #pragma unroll
    for (int ks = 0; ks < 64; ks += 32) {
      bf16x8_t a[4], b[4];
      #pragma unroll
      for (int i = 0; i < 4; ++i) {
        a[i] = *(const bf16x8_t*)&As[(wr + i * 16 + m16) * 72 + ks + q * 8];
        b[i] = *(const bf16x8_t*)&Bs[(wc + i * 16 + m16) * 72 + ks + q * 8];
      }
      #pragma unroll
      for (int i = 0; i < 4; ++i)
        #pragma unroll
        for (int j = 0; j < 4; ++j)
          acc[i][j] = __builtin_amdgcn_mfma_f32_16x16x32_bf16(a[i], b[j], acc[i][j], 0, 0, 0);
    }
    __syncthreads();
  }
  const float* b1e = b1 + (size_t)e * HID;
  #pragma unroll
  for (int i = 0; i < 4; ++i) {
    #pragma unroll
    for (int r = 0; r < 4; ++r) {
      int row = wr + i * 16 + q * 4 + r;
      if (row0 + row < c_e) {
        size_t slot = (size_t)(off + row0 + row);
        #pragma unroll
        for (int j = 0; j < 4; ++j) {
          int col = col0 + wc + j * 16 + m16;
          float v = acc[i][j][r] + b1e[col];
          He[slot * HID + col] = f2bf(gelu_exact(v));
        }
      }
    }
  }
}

// ---------------- GEMM2: acc[token] += gate * (He @ W2[e] + b2[e]) ----------------
__global__ __launch_bounds__(256, 2) void expert_gemm2(
    const unsigned short* __restrict__ He,    // [CAP][H] bf16
    const unsigned short* __restrict__ W2T,   // [E][D][H] bf16
    const float* __restrict__ b2,             // [E][D]
    const int* __restrict__ cnt, const int* __restrict__ offs,
    const int* __restrict__ row_token, const float* __restrict__ row_gate,
    float* __restrict__ accb) {               // [N][D] fp32
  __shared__ unsigned short As[128 * 72];
  __shared__ unsigned short Bs[128 * 72];
  __shared__ int toks[128];
  __shared__ float gts[128];
  int e = blockIdx.z;
  int c_e = cnt[e];
  int row0 = blockIdx.x * 128;
  if (row0 >= c_e) return;
  int col0 = blockIdx.y * 128;
  int off = offs[e];
  int tid = threadIdx.x;
  if (tid < 128) {
    int r = row0 + tid;
    bool val = r < c_e;
    toks[tid] = val ? row_token[off + r] : 0;
    gts[tid] = val ? row_gate[off + r] : 0.f;
  }
  __syncthreads();
  f32x4_t zero4 = {0.f, 0.f, 0.f, 0.f};
  f32x4_t acc[4][4];
  #pragma unroll
  for (int i = 0; i < 4; ++i)
    #pragma unroll
    for (int j = 0; j < 4; ++j) acc[i][j] = zero4;
  const unsigned short* Ag = He + (size_t)(off + row0) * HID;
  const unsigned short* Bg = W2T + (size_t)e * DIM * HID;
  int wid = tid >> 6, lane = tid & 63;
  int wr = (wid & 1) << 6, wc = (wid >> 1) << 6;
  int m16 = lane & 15, q = lane >> 4;
  for (int k0 = 0; k0 < HID; k0 += 64) {
    #pragma unroll
    for (int i = 0; i < 4; ++i) {
      int c = tid + (i << 8);
      int r = c >> 3, kc = c & 7;
      *(uint4*)&As[r * 72 + kc * 8] = *(const uint4*)&Ag[(size_t)r * HID + k0 + kc * 8];
      *(uint4*)&Bs[r * 72 + kc * 8] = *(const uint4*)&Bg[(size_t)(col0 + r) * HID + k0 + kc * 8];
    }
    __syncthreads();
    #pragma unroll
    for (int ks = 0; ks < 64; ks += 32) {
      bf16x8_t a[4], b[4];
      #pragma unroll
      for (int i = 0; i < 4; ++i) {
        a[i] = *(const bf16x8_t*)&As[(wr + i * 16 + m16) * 72 + ks + q * 8];
        b[i] = *(const bf16x8_t*)&Bs[(wc + i * 16 + m16) * 72 + ks + q * 8];
      }
      #pragma unroll
      for (int i = 0; i < 4; ++i)
        #pragma unroll
        for (int j = 0; j < 4; ++j)
          acc[i][j] = __builtin_amdgcn_mfma_f32_16x16x32_bf16(a[i], b[j], acc[i][j], 0, 0, 0);
    }
    __syncthreads();
  }
  const float* b2e = b2 + (size_t)e * DIM;
  #pragma unroll
  for (int i = 0; i < 4; ++i) {
    #pragma unroll
    for (int r = 0; r < 4; ++r) {
      int row = wr + i * 16 + q * 4 + r;
      if (row0 + row < c_e) {
        int tok = toks[row];
        float g = gts[row];
        #pragma unroll
        for (int j = 0; j < 4; ++j) {
          int col = col0 + wc + j * 16 + m16;
          float v = acc[i][j][r] + b2e[col];
          atomicAdd(&accb[(size_t)tok * DIM + col], g * v);
        }
      }
    }
  }
}

// ---------------- residual + LayerNorm ----------------
__global__ __launch_bounds__(256) void ln_kernel(
    const float* __restrict__ x, const float* __restrict__ accb,
    const float* __restrict__ gamma, const float* __restrict__ beta,
    float* __restrict__ out) {
  int n = blockIdx.x, tid = threadIdx.x;
  const float* xr = x + (size_t)n * DIM;
  const float* ar = accb + (size_t)n * DIM;
  float z[4], s = 0.f, s2 = 0.f;
  #pragma unroll
  for (int jj = 0; jj < 4; ++jj) {
    int d = tid + (jj << 8);
    float v = xr[d] + ar[d];
    z[jj] = v; s += v; s2 += v * v;
  }
  for (int o = 32; o > 0; o >>= 1) { s += __shfl_down(s, o, 64); s2 += __shfl_down(s2, o, 64); }
  __shared__ float rs[4], rs2[4];
  int wid = tid >> 6, lane = tid & 63;
  if (lane == 0) { rs[wid] = s; rs2[wid] = s2; }
  __syncthreads();
  float ts = rs[0] + rs[1] + rs[2] + rs[3];
  float ts2 = rs2[0] + rs2[1] + rs2[2] + rs2[3];
  float mu = ts * (1.f / DIM);
  float var = ts2 * (1.f / DIM) - mu * mu;
  float rstd = rsqrtf(var + 1e-5f);
  float* orow = out + (size_t)n * DIM;
  #pragma unroll
  for (int jj = 0; jj < 4; ++jj) {
    int d = tid + (jj << 8);
    orow[d] = (z[jj] - mu) * rstd * gamma[d] + beta[d];
  }
}

extern "C" void kernel_launch(void* const* d_in, const int* in_sizes, int n_in,
                              void* d_out, int out_size, void* d_ws, size_t ws_size,
                              hipStream_t stream) {
  const float* x     = (const float*)d_in[0];
  const float* gW    = (const float*)d_in[1];
  const float* gb    = (const float*)d_in[2];
  const float* W1    = (const float*)d_in[3];
  const float* b1    = (const float*)d_in[4];
  const float* W2    = (const float*)d_in[5];
  const float* b2    = (const float*)d_in[6];
  const float* gamma = (const float*)d_in[7];
  const float* beta  = (const float*)d_in[8];
  float* out = (float*)d_out;

  // workspace layout (~185 MB), all chunks 16B-aligned
  char* w = (char*)d_ws;
  unsigned short* xbf = (unsigned short*)w; w += (size_t)N_TOK * DIM * 2;
  unsigned short* W1T = (unsigned short*)w; w += (size_t)NE * HID * DIM * 2;
  unsigned short* W2T = (unsigned short*)w; w += (size_t)NE * DIM * HID * 2;
  unsigned short* He  = (unsigned short*)w; w += (size_t)CAP * HID * 2;
  float* accb         = (float*)w;          w += (size_t)N_TOK * DIM * 4;
  int*   row_token    = (int*)w;            w += (size_t)CAP * 4;
  float* row_gate     = (float*)w;          w += (size_t)CAP * 4;
  int*   tok_e        = (int*)w;            w += (size_t)NPAIR * 4;
  float* tok_g        = (float*)w;          w += (size_t)NPAIR * 4;
  float* imp          = (float*)w;          // 8 floats
  float* ent_sum      = imp + 8;            // 1 float (+7 pad)
  int*   cntp         = (int*)(imp + 16);   // 8 ints
  int*   cursor       = cntp + 8;           // 8 ints
  int*   offs         = cursor + 8;         // 8 ints

  hipMemsetAsync(accb, 0, (size_t)N_TOK * DIM * 4, stream);
  hipMemsetAsync(imp, 0, 256, stream);      // imp, ent_sum, cnt (cursor/offs set by finalize)

  cvt_x_kernel<<<N_TOK * DIM / (256 * 4), 256, 0, stream>>>(x, xbf);
  transpose_kernel<<<dim3(HID / 32, DIM / 32, NE), 256, 0, stream>>>(W1, W1T, DIM, HID);
  transpose_kernel<<<dim3(DIM / 32, HID / 32, NE), 256, 0, stream>>>(W2, W2T, HID, DIM);
  router_kernel<<<N_TOK / 4, 256, 0, stream>>>(x, gW, gb, tok_e, tok_g, cntp, imp, ent_sum);
  finalize_kernel<<<1, 64, 0, stream>>>(cntp, offs, cursor, imp, ent_sum, out + TAIL);
  scatter_kernel<<<N_TOK / 256, 256, 0, stream>>>(tok_e, tok_g, cursor, row_token, row_gate);
  expert_gemm1<<<dim3(64, HID / 128, NE), 256, 0, stream>>>(xbf, W1T, b1, cntp, offs, row_token, He);
  expert_gemm2<<<dim3(64, DIM / 128, NE), 256, 0, stream>>>(He, W2T, b2, cntp, offs, row_token, row_gate, accb);
  ln_kernel<<<N_TOK, 256, 0, stream>>>(x, accb, gamma, beta, out);
}

// Round 2
// 721.883 us; speedup vs baseline: 2.4492x; 2.4492x over previous
//
#include <hip/hip_runtime.h>
#include <math.h>

#define N_TOK 8192
#define DIM   1024
#define HID   2048
#define NE    8
#define NPAIR (N_TOK * 2)          // 16384 (token, expert) pairs exactly
#define CAP   (NPAIR + 128)        // pad so last row-tile reads stay in bounds
#define TAIL  (N_TOK * DIM)        // offset of scalar outputs in d_out

typedef __bf16 bf16x8_t __attribute__((ext_vector_type(8)));
typedef float  f32x4_t  __attribute__((ext_vector_type(4)));

__device__ __forceinline__ unsigned short f2bf(float f) {
  union { float f; unsigned u; } v; v.f = f;
  unsigned r = v.u + 0x7fffu + ((v.u >> 16) & 1u);   // RNE
  return (unsigned short)(r >> 16);
}

__device__ __forceinline__ float bf2f(unsigned short h) {
  union { unsigned u; float f; } v; v.u = ((unsigned)h) << 16;
  return v.f;
}

__device__ __forceinline__ float gelu_exact(float v) {
  return 0.5f * v * (1.f + erff(v * 0.70710678118654752440f));
}

// ---------------- x -> bf16 ----------------
__global__ __launch_bounds__(256) void cvt_x_kernel(const float* __restrict__ x,
                                                    unsigned short* __restrict__ xbf) {
  size_t base = (size_t)(blockIdx.x * 256 + threadIdx.x) * 4;
  float4 v = *(const float4*)(x + base);
  ushort4 o;
  o.x = f2bf(v.x); o.y = f2bf(v.y); o.z = f2bf(v.z); o.w = f2bf(v.w);
  *(ushort4*)(xbf + base) = o;
}

// ---------------- fp32 [z][R][C] -> bf16 [z][C][R] (LDS-tiled) ----------------
__global__ __launch_bounds__(256) void transpose_kernel(const float* __restrict__ src,
                                                        unsigned short* __restrict__ dst,
                                                        int R, int C) {
  __shared__ float tile[32][33];
  int z = blockIdx.z;
  const float* s = src + (size_t)z * R * C;
  unsigned short* d = dst + (size_t)z * R * C;
  int c0 = blockIdx.x * 32, r0 = blockIdx.y * 32;
  int tx = threadIdx.x & 31, ty = threadIdx.x >> 5;   // 32 x 8
  #pragma unroll
  for (int i = 0; i < 32; i += 8)
    tile[ty + i][tx] = s[(size_t)(r0 + ty + i) * C + c0 + tx];
  __syncthreads();
  #pragma unroll
  for (int i = 0; i < 32; i += 8)
    d[(size_t)(c0 + ty + i) * R + r0 + tx] = f2bf(tile[tx][ty + i]);
}

// ---------------- router: logits (fp32), top-2, softmax, aux stats ----------------
// Atomic discipline (R2 fix): imp/ent accumulate in lane-0 registers per wave,
// cnt in LDS per block; ONE global atomic per counter per block (128 blocks x 9
// atomics ~1.2k total, vs 90k same-address atomics in R1 -> 964us stall).
#define R_BLOCKS 128
#define R_TPW    (N_TOK / (R_BLOCKS * 4))   // 16 tokens per wave
__global__ __launch_bounds__(256) void router_kernel(
    const float* __restrict__ x, const float* __restrict__ gW, const float* __restrict__ gb,
    int* __restrict__ tok_e, float* __restrict__ tok_g,
    int* __restrict__ cnt, float* __restrict__ imp, float* __restrict__ ent_sum) {
  __shared__ int s_cnt[NE];
  __shared__ float s_imp[NE];
  __shared__ float s_ent;
  int tid = threadIdx.x;
  if (tid < NE) { s_cnt[tid] = 0; s_imp[tid] = 0.f; }
  if (tid == 0) s_ent = 0.f;
  __syncthreads();
  int wid = tid >> 6, lane = tid & 63;
  int t0 = (blockIdx.x * 4 + wid) * R_TPW;
  float imp_loc[8] = {0.f, 0.f, 0.f, 0.f, 0.f, 0.f, 0.f, 0.f};
  float ent_loc = 0.f;
  for (int t = 0; t < R_TPW; ++t) {
    int n = t0 + t;
    const float* xr = x + (size_t)n * DIM;
    float p[8] = {0.f, 0.f, 0.f, 0.f, 0.f, 0.f, 0.f, 0.f};
    #pragma unroll
    for (int it = 0; it < DIM / 64; ++it) {
      int d = lane + (it << 6);
      float xv = xr[d];
      const float4* g4 = (const float4*)(gW + (size_t)d * NE);
      float4 a = g4[0], b = g4[1];
      p[0] += xv * a.x; p[1] += xv * a.y; p[2] += xv * a.z; p[3] += xv * a.w;
      p[4] += xv * b.x; p[5] += xv * b.y; p[6] += xv * b.z; p[7] += xv * b.w;
    }
    #pragma unroll
    for (int e = 0; e < 8; ++e)
      for (int o = 32; o > 0; o >>= 1) p[e] += __shfl_down(p[e], o, 64);
    if (lane == 0) {
      float lg[8];
      #pragma unroll
      for (int e = 0; e < 8; ++e) lg[e] = p[e] + gb[e];
      int i0 = 0;
      #pragma unroll
      for (int e = 1; e < 8; ++e) if (lg[e] > lg[i0]) i0 = e;   // ties -> lowest idx
      int i1 = (i0 == 0) ? 1 : 0;
      #pragma unroll
      for (int e = 0; e < 8; ++e) if (e != i0 && lg[e] > lg[i1]) i1 = e;
      float d1 = expf(lg[i1] - lg[i0]);
      float g0 = 1.f / (1.f + d1);
      float g1 = d1 * g0;
      tok_e[2 * n] = i0; tok_e[2 * n + 1] = i1;
      tok_g[2 * n] = g0; tok_g[2 * n + 1] = g1;
      atomicAdd(&s_cnt[i0], 1);            // LDS atomic — cheap
      atomicAdd(&s_cnt[i1], 1);
      float mx = lg[i0], s = 0.f, pe[8];
      #pragma unroll
      for (int e = 0; e < 8; ++e) { pe[e] = expf(lg[e] - mx); s += pe[e]; }
      float inv = 1.f / s;
      #pragma unroll
      for (int e = 0; e < 8; ++e) {
        float pr = pe[e] * inv;
        imp_loc[e] += pr;
        ent_loc -= pr * logf(pr + 1e-8f);
      }
    }
  }
  if (lane == 0) {
    #pragma unroll
    for (int e = 0; e < 8; ++e) atomicAdd(&s_imp[e], imp_loc[e]);  // LDS
    atomicAdd(&s_ent, ent_loc);
  }
  __syncthreads();
  const float invN = 1.f / (float)N_TOK;
  if (tid < NE) {
    atomicAdd(&cnt[tid], s_cnt[tid]);
    atomicAdd(&imp[tid], s_imp[tid] * invN);
  }
  if (tid == NE) atomicAdd(ent_sum, s_ent * invN);
}

// ---------------- finalize: offsets/cursors + scalar outputs ----------------
__global__ void finalize_kernel(const int* __restrict__ cnt, int* __restrict__ offs,
                                int* __restrict__ cursor, const float* __restrict__ imp,
                                const float* __restrict__ ent_sum, float* __restrict__ out_tail) {
  if (threadIdx.x == 0) {
    int off = 0; float bal = 0.f, util = 0.f;
    for (int e = 0; e < NE; ++e) {
      offs[e] = off; cursor[e] = off; off += cnt[e];
      float ld = (float)cnt[e] * (1.f / (float)N_TOK);
      float im = imp[e];
      out_tail[3 + e] = ld;        // load
      out_tail[11 + e] = im;       // importance
      bal += im * ld;
      util -= ld * logf(ld + 1e-8f);
    }
    out_tail[0] = (float)NE * bal; // balance_loss
    out_tail[1] = *ent_sum;        // entropy
    out_tail[2] = util;            // utilization_entropy
  }
}

// ---------------- scatter pairs into expert buckets ----------------
// R2 fix: per-block LDS histogram + one cursor reservation per expert per block
// (32 blocks x 8 = 256 global atomics vs 16k same-address atomics in R1).
// Also emits pair_slot (token -> slot inverse map) for the gather-LN epilogue.
__global__ __launch_bounds__(256) void scatter_kernel(
    const int* __restrict__ tok_e, const float* __restrict__ tok_g,
    int* __restrict__ cursor, int* __restrict__ row_token, float* __restrict__ row_gate,
    int* __restrict__ pair_slot) {
  __shared__ int s_cnt[NE], s_base[NE], s_rank[NE];
  int tid = threadIdx.x;
  if (tid < NE) { s_cnt[tid] = 0; s_rank[tid] = 0; }
  __syncthreads();
  int n = blockIdx.x * 256 + tid;
  int e0 = tok_e[2 * n], e1 = tok_e[2 * n + 1];
  atomicAdd(&s_cnt[e0], 1);
  atomicAdd(&s_cnt[e1], 1);
  __syncthreads();
  if (tid < NE) s_base[tid] = atomicAdd(&cursor[tid], s_cnt[tid]);
  __syncthreads();
  int r0 = atomicAdd(&s_rank[e0], 1);
  int s0 = s_base[e0] + r0;
  row_token[s0] = n; row_gate[s0] = tok_g[2 * n]; pair_slot[2 * n] = s0;
  int r1 = atomicAdd(&s_rank[e1], 1);
  int s1 = s_base[e1] + r1;
  row_token[s1] = n; row_gate[s1] = tok_g[2 * n + 1]; pair_slot[2 * n + 1] = s1;
}

// ---------------- GEMM1: He = gelu(X_gather @ W1[e] + b1[e]), bf16 out ----------------
__global__ __launch_bounds__(256, 2) void expert_gemm1(
    const unsigned short* __restrict__ xbf,   // [N][D] bf16
    const unsigned short* __restrict__ W1T,   // [E][H][D] bf16
    const float* __restrict__ b1,             // [E][H]
    const int* __restrict__ cnt, const int* __restrict__ offs,
    const int* __restrict__ row_token,
    unsigned short* __restrict__ He) {        // [CAP][H] bf16
  __shared__ unsigned short As[128 * 72];
  __shared__ unsigned short Bs[128 * 72];
  __shared__ int toks[128];
  int e = blockIdx.z;
  int c_e = cnt[e];
  int row0 = blockIdx.x * 128;
  if (row0 >= c_e) return;
  int col0 = blockIdx.y * 128;
  int off = offs[e];
  int tid = threadIdx.x;
  if (tid < 128) {
    int r = row0 + tid;
    toks[tid] = (r < c_e) ? row_token[off + r] : 0;
  }
  __syncthreads();
  f32x4_t zero4 = {0.f, 0.f, 0.f, 0.f};
  f32x4_t acc[4][4];
  #pragma unroll
  for (int i = 0; i < 4; ++i)
    #pragma unroll
    for (int j = 0; j < 4; ++j) acc[i][j] = zero4;
  const unsigned short* Bg = W1T + (size_t)e * HID * DIM;
  int wid = tid >> 6, lane = tid & 63;
  int wr = (wid & 1) << 6, wc = (wid >> 1) << 6;
  int m16 = lane & 15, q = lane >> 4;
  for (int k0 = 0; k0 < DIM; k0 += 64) {
    #pragma unroll
    for (int i = 0; i < 4; ++i) {
      int c = tid + (i << 8);
      int r = c >> 3, kc = c & 7;
      *(uint4*)&As[r * 72 + kc * 8] = *(const uint4*)&xbf[(size_t)toks[r] * DIM + k0 + kc * 8];
      *(uint4*)&Bs[r * 72 + kc * 8] = *(const uint4*)&Bg[(size_t)(col0 + r) * DIM + k0 + kc * 8];
    }
    __syncthreads();
    #pragma unroll
    for (int ks = 0; ks < 64; ks += 32) {
      bf16x8_t a[4], b[4];
      #pragma unroll
      for (int i = 0; i < 4; ++i) {
        a[i] = *(const bf16x8_t*)&As[(wr + i * 16 + m16) * 72 + ks + q * 8];
        b[i] = *(const bf16x8_t*)&Bs[(wc + i * 16 + m16) * 72 + ks + q * 8];
      }
      #pragma unroll
      for (int i = 0; i < 4; ++i)
        #pragma unroll
        for (int j = 0; j < 4; ++j)
          acc[i][j] = __builtin_amdgcn_mfma_f32_16x16x32_bf16(a[i], b[j], acc[i][j], 0, 0, 0);
    }
    __syncthreads();
  }
  const float* b1e = b1 + (size_t)e * HID;
  #pragma unroll
  for (int i = 0; i < 4; ++i) {
    #pragma unroll
    for (int r = 0; r < 4; ++r) {
      int row = wr + i * 16 + q * 4 + r;
      if (row0 + row < c_e) {
        size_t slot = (size_t)(off + row0 + row);
        #pragma unroll
        for (int j = 0; j < 4; ++j) {
          int col = col0 + wc + j * 16 + m16;
          float v = acc[i][j][r] + b1e[col];
          He[slot * HID + col] = f2bf(gelu_exact(v));
        }
      }
    }
  }
}

// ---------------- GEMM2: y[slot] = He @ W2[e]  (raw, bf16; bias+gate in LN) ----------------
// R2 fix: direct per-slot store replaces 16.7M atomicAdd into accb + its 33MB memset.
__global__ __launch_bounds__(256, 2) void expert_gemm2(
    const unsigned short* __restrict__ He,    // [CAP][H] bf16
    const unsigned short* __restrict__ W2T,   // [E][D][H] bf16
    const int* __restrict__ cnt, const int* __restrict__ offs,
    unsigned short* __restrict__ yb) {        // [CAP][D] bf16
  __shared__ unsigned short As[128 * 72];
  __shared__ unsigned short Bs[128 * 72];
  int e = blockIdx.z;
  int c_e = cnt[e];
  int row0 = blockIdx.x * 128;
  if (row0 >= c_e) return;
  int col0 = blockIdx.y * 128;
  int off = offs[e];
  int tid = threadIdx.x;
  f32x4_t zero4 = {0.f, 0.f, 0.f, 0.f};
  f32x4_t acc[4][4];
  #pragma unroll
  for (int i = 0; i < 4; ++i)
    #pragma unroll
    for (int j = 0; j < 4; ++j) acc[i][j] = zero4;
  const unsigned short* Ag = He + (size_t)(off + row0) * HID;
  const unsigned short* Bg = W2T + (size_t)e * DIM * HID;
  int wid = tid >> 6, lane = tid & 63;
  int wr = (wid & 1) << 6, wc = (wid >> 1) << 6;
  int m16 = lane & 15, q = lane >> 4;
  for (int k0 = 0; k0 < HID; k0 += 64) {
    #pragma unroll
    for (int i = 0; i < 4; ++i) {
      int c = tid + (i << 8);
      int r = c >> 3, kc = c & 7;
      *(uint4*)&As[r * 72 + kc * 8] = *(const uint4*)&Ag[(size_t)r * HID + k0 + kc * 8];
      *(uint4*)&Bs[r * 72 + kc * 8] = *(const uint4*)&Bg[(size_t)(col0 + r) * HID + k0 + kc * 8];
    }
    __syncthreads();
    #pragma unroll
    for (int ks = 0; ks < 64; ks += 32) {
      bf16x8_t a[4], b[4];
      #pragma unroll
      for (int i = 0; i < 4; ++i) {
        a[i] = *(const bf16x8_t*)&As[(wr + i * 16 + m16) * 72 + ks + q * 8];
        b[i] = *(const bf16x8_t*)&Bs[(wc + i * 16 + m16) * 72 + ks + q * 8];
      }
      #pragma unroll
      for (int i = 0; i < 4; ++i)
        #pragma unroll
        for (int j = 0; j < 4; ++j)
          acc[i][j] = __builtin_amdgcn_mfma_f32_16x16x32_bf16(a[i], b[j], acc[i][j], 0, 0, 0);
    }
    __syncthreads();
  }
  #pragma unroll
  for (int i = 0; i < 4; ++i) {
    #pragma unroll
    for (int r = 0; r < 4; ++r) {
      int row = wr + i * 16 + q * 4 + r;
      if (row0 + row < c_e) {
        size_t slot = (size_t)(off + row0 + row);
        #pragma unroll
        for (int j = 0; j < 4; ++j) {
          int col = col0 + wc + j * 16 + m16;
          yb[slot * DIM + col] = f2bf(acc[i][j][r]);
        }
      }
    }
  }
}

// ---------------- gather + gate + bias + residual + LayerNorm ----------------
__global__ __launch_bounds__(256) void ln_kernel(
    const float* __restrict__ x, const unsigned short* __restrict__ yb,
    const int* __restrict__ tok_e, const float* __restrict__ tok_g,
    const int* __restrict__ pair_slot, const float* __restrict__ b2,
    const float* __restrict__ gamma, const float* __restrict__ beta,
    float* __restrict__ out) {
  int n = blockIdx.x, tid = threadIdx.x;
  int e0 = tok_e[2 * n], e1 = tok_e[2 * n + 1];
  float g0 = tok_g[2 * n], g1 = tok_g[2 * n + 1];
  size_t s0 = (size_t)pair_slot[2 * n], s1 = (size_t)pair_slot[2 * n + 1];
  const float* xr = x + (size_t)n * DIM;
  const unsigned short* y0 = yb + s0 * DIM;
  const unsigned short* y1 = yb + s1 * DIM;
  const float* b2e0 = b2 + (size_t)e0 * DIM;
  const float* b2e1 = b2 + (size_t)e1 * DIM;
  float z[4], s = 0.f, s2 = 0.f;
  #pragma unroll
  for (int jj = 0; jj < 4; ++jj) {
    int d = tid + (jj << 8);
    float v = xr[d] + g0 * (bf2f(y0[d]) + b2e0[d]) + g1 * (bf2f(y1[d]) + b2e1[d]);
    z[jj] = v; s += v; s2 += v * v;
  }
  for (int o = 32; o > 0; o >>= 1) { s += __shfl_down(s, o, 64); s2 += __shfl_down(s2, o, 64); }
  __shared__ float rs[4], rs2[4];
  int wid = tid >> 6, lane = tid & 63;
  if (lane == 0) { rs[wid] = s; rs2[wid] = s2; }
  __syncthreads();
  float ts = rs[0] + rs[1] + rs[2] + rs[3];
  float ts2 = rs2[0] + rs2[1] + rs2[2] + rs2[3];
  float mu = ts * (1.f / DIM);
  float var = ts2 * (1.f / DIM) - mu * mu;
  float rstd = rsqrtf(var + 1e-5f);
  float* orow = out + (size_t)n * DIM;
  #pragma unroll
  for (int jj = 0; jj < 4; ++jj) {
    int d = tid + (jj << 8);
    orow[d] = (z[jj] - mu) * rstd * gamma[d] + beta[d];
  }
}

extern "C" void kernel_launch(void* const* d_in, const int* in_sizes, int n_in,
                              void* d_out, int out_size, void* d_ws, size_t ws_size,
                              hipStream_t stream) {
  const float* x     = (const float*)d_in[0];
  const float* gW    = (const float*)d_in[1];
  const float* gb    = (const float*)d_in[2];
  const float* W1    = (const float*)d_in[3];
  const float* b1    = (const float*)d_in[4];
  const float* W2    = (const float*)d_in[5];
  const float* b2    = (const float*)d_in[6];
  const float* gamma = (const float*)d_in[7];
  const float* beta  = (const float*)d_in[8];
  float* out = (float*)d_out;

  // workspace layout (~182 MB), all chunks 16B-aligned
  char* w = (char*)d_ws;
  unsigned short* xbf = (unsigned short*)w; w += (size_t)N_TOK * DIM * 2;
  unsigned short* W1T = (unsigned short*)w; w += (size_t)NE * HID * DIM * 2;
  unsigned short* W2T = (unsigned short*)w; w += (size_t)NE * DIM * HID * 2;
  unsigned short* He  = (unsigned short*)w; w += (size_t)CAP * HID * 2;
  unsigned short* yb  = (unsigned short*)w; w += (size_t)CAP * DIM * 2;
  int*   row_token    = (int*)w;            w += (size_t)CAP * 4;
  float* row_gate     = (float*)w;          w += (size_t)CAP * 4;
  int*   tok_e        = (int*)w;            w += (size_t)NPAIR * 4;
  float* tok_g        = (float*)w;          w += (size_t)NPAIR * 4;
  int*   pair_slot    = (int*)w;            w += (size_t)NPAIR * 4;
  float* imp          = (float*)w;          // 8 floats
  float* ent_sum      = imp + 8;            // 1 float (+7 pad)
  int*   cntp         = (int*)(imp + 16);   // 8 ints
  int*   cursor       = cntp + 8;           // 8 ints
  int*   offs         = cursor + 8;         // 8 ints

  hipMemsetAsync(imp, 0, 256, stream);      // imp, ent_sum, cnt (cursor/offs set by finalize)

  cvt_x_kernel<<<N_TOK * DIM / (256 * 4), 256, 0, stream>>>(x, xbf);
  transpose_kernel<<<dim3(HID / 32, DIM / 32, NE), 256, 0, stream>>>(W1, W1T, DIM, HID);
  transpose_kernel<<<dim3(DIM / 32, HID / 32, NE), 256, 0, stream>>>(W2, W2T, HID, DIM);
  router_kernel<<<R_BLOCKS, 256, 0, stream>>>(x, gW, gb, tok_e, tok_g, cntp, imp, ent_sum);
  finalize_kernel<<<1, 64, 0, stream>>>(cntp, offs, cursor, imp, ent_sum, out + TAIL);
  scatter_kernel<<<N_TOK / 256, 256, 0, stream>>>(tok_e, tok_g, cursor, row_token, row_gate, pair_slot);
  expert_gemm1<<<dim3(64, HID / 128, NE), 256, 0, stream>>>(xbf, W1T, b1, cntp, offs, row_token, He);
  expert_gemm2<<<dim3(64, DIM / 128, NE), 256, 0, stream>>>(He, W2T, cntp, offs, yb);
  ln_kernel<<<N_TOK, 256, 0, stream>>>(x, yb, tok_e, tok_g, pair_slot, b2, gamma, beta, out);
}